// Round 5
// baseline (187.102 us; speedup 1.0000x reference)
//
#include <hip/hip_runtime.h>
#include <hip/hip_bf16.h>

#define SEQ 2048

typedef short s4v __attribute__((ext_vector_type(4)));
typedef float f32x4 __attribute__((ext_vector_type(4)));
typedef short s8v __attribute__((ext_vector_type(8)));

using bf16 = __hip_bfloat16;
using ull = unsigned long long;

__device__ __forceinline__ float wred_sum(float v){
#pragma unroll
  for (int i = 1; i < 64; i <<= 1) v += __shfl_xor(v, i, 64);
  return v;
}

__device__ __forceinline__ float wred_max(float v){
#pragma unroll
  for (int i = 1; i < 64; i <<= 1) v = fmaxf(v, __shfl_xor(v, i, 64));
  return v;
}

// Detect whether a "float" input buffer is really f32 (1) or bf16 (0).
__device__ __forceinline__ int detect_f32(const void* xraw){
  const unsigned short* p = (const unsigned short*)xraw;
  const int lane = threadIdx.x & 63;
  float mx = 0.f;
#pragma unroll
  for (int i = 0; i < 2; ++i){
    unsigned u = ((unsigned)p[lane * 2 + i]) << 16;
    float f = fabsf(__uint_as_float(u));
    if (!(f < 1e30f)) f = 1e30f;       // NaN/Inf -> large
    mx = fmaxf(mx, f);
  }
  mx = wred_max(mx);
  return mx > 1e3f ? 1 : 0;
}

template<int F32>
__device__ __forceinline__ float ldf(const void* p, int i){
  if constexpr (F32) return ((const float*)p)[i];
  else return __bfloat162float(((const bf16*)p)[i]);
}

// log2(e)/sqrt(dk) folded into Q at projection time
#define QSCALE 0.5101129340352065f

// ---------------- Kernel P: fused mask-pack + LN1/QKV ----------------
// blocks 0..2047: bit-pack mask rows (linear reads, 64MB->2MB, BW-bound)
// blocks 2048..4095: LN1 + QKV projection (VALU-bound) -- overlap on chip.
template<int F32>
__device__ __forceinline__ void ln_qkv_body(
    const void* x,
    const void* Wq, const void* bq,
    const void* Wk, const void* bk,
    const void* Wv, const void* bv,
    const void* ln1w, const void* ln1b,
    float* x1f, bf16* Qb, bf16* Kb, bf16* Vb, float (*xs)[64])
{
  const int w = threadIdx.x >> 6, lane = threadIdx.x & 63;
  const int row = (blockIdx.x - 2048) * 4 + w;        // 0..8191 (= b*2048+s)
  float xv = ldf<F32>(x, row * 64 + lane);
  float mu = wred_sum(xv) * 0.015625f;
  float dv = xv - mu;
  float var = wred_sum(dv * dv) * 0.015625f;
  float x1 = dv * rsqrtf(var + 1e-5f) * ldf<F32>(ln1w, lane) + ldf<F32>(ln1b, lane);
  x1f[(size_t)row * 64 + lane] = x1;
  xs[w][lane] = x1;
  __syncthreads();
  float q = ldf<F32>(bq, lane);
  float k = ldf<F32>(bk, lane);
  float v = ldf<F32>(bv, lane);
#pragma unroll 16
  for (int d = 0; d < 64; ++d){
    float xd = xs[w][d];                              // LDS broadcast
    q += xd * ldf<F32>(Wq, d * 64 + lane);            // contiguous per d
    k += xd * ldf<F32>(Wk, d * 64 + lane);
    v += xd * ldf<F32>(Wv, d * 64 + lane);
  }
  Qb[(size_t)row * 64 + lane] = __float2bfloat16(q * QSCALE);  // pre-scaled
  Kb[(size_t)row * 64 + lane] = __float2bfloat16(k);
  Vb[(size_t)row * 64 + lane] = __float2bfloat16(v);
}

__global__ __launch_bounds__(256) void k_prep(
    const int* __restrict__ mask, ull* __restrict__ pm,
    const void* x, const void* Wq, const void* bq, const void* Wk, const void* bk,
    const void* Wv, const void* bv, const void* ln1w, const void* ln1b,
    float* x1f, bf16* Qb, bf16* Kb, bf16* Vb)
{
  __shared__ float xs[4][64];
  const int w = threadIdx.x >> 6, lane = threadIdx.x & 63;
  if (blockIdx.x < 2048){
    const int row = blockIdx.x * 4 + w;               // 0..8191 (= b*2048+q)
    const int* rp = mask + (size_t)row * SEQ;
    ull* op = pm + (size_t)row * 32;
#pragma unroll
    for (int it = 0; it < 8; ++it){
      const int c0 = it * 256 + lane;
      ull m0 = __ballot(rp[c0] == 1);
      ull m1 = __ballot(rp[c0 + 64] == 1);
      ull m2 = __ballot(rp[c0 + 128] == 1);
      ull m3 = __ballot(rp[c0 + 192] == 1);
      if (lane == 0){
        op[it * 4 + 0] = m0; op[it * 4 + 1] = m1;
        op[it * 4 + 2] = m2; op[it * 4 + 3] = m3;
      }
    }
    return;
  }
  if (detect_f32(x))
    ln_qkv_body<1>(x, Wq, bq, Wk, bk, Wv, bv, ln1w, ln1b, x1f, Qb, Kb, Vb, xs);
  else
    ln_qkv_body<0>(x, Wq, bq, Wk, bk, Wv, bv, ln1w, ln1b, x1f, Qb, Kb, Vb, xs);
}

// ---------------- Kernel A2: transpose V -> Vt9[bh][9][S], row 8 = ones ---------
__global__ __launch_bounds__(256) void k_vt(const bf16* __restrict__ Vb, bf16* __restrict__ Vt9)
{
  const int idx = blockIdx.x;            // 256 blocks
  const int sc = idx & 7;                // s-chunk (8 x 256)
  const int bh = idx >> 3;               // b*8+h, 0..31
  const int s0 = sc * 256;
  const int b = bh >> 3, h = bh & 7;
  __shared__ unsigned short tile[256][9];   // pad to break bank alignment
  const int t = threadIdx.x;
  s8v vrow = *reinterpret_cast<const s8v*>(Vb + ((size_t)(b * SEQ + s0 + t)) * 64 + h * 8);
#pragma unroll
  for (int i = 0; i < 8; ++i) tile[t][i] = (unsigned short)vrow[i];
  __syncthreads();
  const int d = t >> 5, j = t & 31;      // d 0..7, j 0..31 (8 s-values each)
  unsigned short tmp[8];
#pragma unroll
  for (int i = 0; i < 8; ++i) tmp[i] = tile[j * 8 + i][d];
  uint4 o;
  o.x = (unsigned)tmp[0] | ((unsigned)tmp[1] << 16);
  o.y = (unsigned)tmp[2] | ((unsigned)tmp[3] << 16);
  o.z = (unsigned)tmp[4] | ((unsigned)tmp[5] << 16);
  o.w = (unsigned)tmp[6] | ((unsigned)tmp[7] << 16);
  *reinterpret_cast<uint4*>(Vt9 + ((size_t)(bh * 9 + d)) * SEQ + s0 + j * 8) = o;
  // ones row (d = 8) for the free softmax denominator
  if (t < 32){
    uint4 ones; ones.x = ones.y = ones.z = ones.w = 0x3F803F80u;   // bf16 1.0 pairs
    *reinterpret_cast<uint4*>(Vt9 + ((size_t)(bh * 9 + 8)) * SEQ + s0 + t * 8) = ones;
  }
}

// ---------------- Kernel B: flash attention, fixed-ref softmax ----------
// 512 thr (8 waves, wave w = head w); 16 queries per block; waves independent.
// No running max / no rescale: p = exp2(score), denominator via V ones-row.
// S^T = K.Q^T via mfma_16x16x16_bf16; D-layout == PV B-operand layout.
__global__ __launch_bounds__(512) void k_attn(
    const bf16* __restrict__ Qb, const bf16* __restrict__ Kb, const bf16* __restrict__ Vt9,
    const ull* __restrict__ pm, float* __restrict__ ctxf)
{
  const int b  = blockIdx.x >> 7;
  const int q0 = (blockIdx.x & 127) * 16;
  const int h  = threadIdx.x >> 6;
  const int lane = threadIdx.x & 63;
  const int g = lane >> 4, qi = lane & 15;
  const int bh = b * 8 + h;

  s4v qf = {0, 0, 0, 0};
  if (g < 2) qf = *reinterpret_cast<const s4v*>(Qb + ((size_t)(b * SEQ + q0 + qi)) * 64 + h * 8 + 4 * g);

  const bf16* kbase = Kb + (size_t)b * SEQ * 64 + h * 8 + 4 * g;   // k>=8 slots: garbage, annihilated by zero Q
  const bf16* vbase = Vt9 + ((size_t)(bh * 9 + qi)) * SEQ;         // qi==8 -> ones row; qi>8 garbage rows (unused)
  const ulonglong2* prow = reinterpret_cast<const ulonglong2*>(pm + (size_t)(b * SEQ + q0 + qi) * 32);

  f32x4 accA = {0.f, 0.f, 0.f, 0.f};
  f32x4 accB = {0.f, 0.f, 0.f, 0.f};
  const f32x4 zf = {0.f, 0.f, 0.f, 0.f};
  const int sh4 = 4 * g;

  for (int kt = 0; kt < SEQ / 128; ++kt){
    const int k0 = kt * 128;
    const ulonglong2 mw = prow[kt];                    // mask bits, cols k0..k0+127
#pragma unroll
    for (int hs = 0; hs < 8; ++hs){
      const int kb = k0 + hs * 16;
      s4v kf = *reinterpret_cast<const s4v*>(kbase + (size_t)(kb + qi) * 64);
      f32x4 st = __builtin_amdgcn_mfma_f32_16x16x16bf16_1k(kf, qf, zf, 0, 0, 0);
      const unsigned b4 = (unsigned)(((hs < 4) ? mw.x : mw.y) >> (16 * (hs & 3) + sh4)) & 0xFu;
      float p0 = (b4 & 1u) ? 0.f : exp2f(st[0]);
      float p1 = (b4 & 2u) ? 0.f : exp2f(st[1]);
      float p2 = (b4 & 4u) ? 0.f : exp2f(st[2]);
      float p3 = (b4 & 8u) ? 0.f : exp2f(st[3]);
      unsigned pw0, pw1;
      asm("v_cvt_pk_bf16_f32 %0, %1, %2" : "=v"(pw0) : "v"(p0), "v"(p1));
      asm("v_cvt_pk_bf16_f32 %0, %1, %2" : "=v"(pw1) : "v"(p2), "v"(p3));
      s4v pf;
      pf[0] = (short)(pw0 & 0xFFFFu); pf[1] = (short)(pw0 >> 16);
      pf[2] = (short)(pw1 & 0xFFFFu); pf[3] = (short)(pw1 >> 16);
      s4v vf = *reinterpret_cast<const s4v*>(vbase + kb + sh4);
      if (hs & 1) accB = __builtin_amdgcn_mfma_f32_16x16x16bf16_1k(vf, pf, accB, 0, 0, 0);
      else        accA = __builtin_amdgcn_mfma_f32_16x16x16bf16_1k(vf, pf, accA, 0, 0, 0);
    }
  }
  f32x4 acc;
  acc[0] = accA[0] + accB[0]; acc[1] = accA[1] + accB[1];
  acc[2] = accA[2] + accB[2]; acc[3] = accA[3] + accB[3];
  // denominator lives in D row 8 (lanes 32..47, reg 0), col = query
  const float s = __shfl(acc[0], 32 + qi, 64);
  if (g < 2){
    const float inv = 1.f / s;
    float4 o;
    o.x = acc[0] * inv; o.y = acc[1] * inv; o.z = acc[2] * inv; o.w = acc[3] * inv;
    *reinterpret_cast<float4*>(ctxf + ((size_t)(bh * SEQ + q0 + qi)) * 8 + 4 * g) = o;
  }
}

// ---------------- Kernel C: Wo + residuals + LN2 + FFN (wave per row) ----------------
template<int F32>
__device__ __forceinline__ void ffn_body(
    const float* ctxf, const float* x1f,
    const void* Wo, const void* bo, const void* W1, const void* b1,
    const void* W2, const void* b2, const void* ln2w, const void* ln2b,
    void* out, float (*cs)[64], float (*x3s)[64], float (*gs)[256])
{
  const int w = threadIdx.x >> 6, c = threadIdx.x & 63;
  const int row = blockIdx.x * 4 + w;
  // ctx.reshape(B,S,D) of contiguous [B,H,S,dk] == flat view: ctx_resh[b,r,c]=ctxf[row*64+c]
  float ctxv = ctxf[(size_t)row * 64 + c];
  float x1v  = x1f[(size_t)row * 64 + c];
  cs[w][c] = ctxv;
  __syncthreads();
  float proj = ldf<F32>(bo, c);
#pragma unroll 8
  for (int d = 0; d < 64; ++d) proj += cs[w][d] * ldf<F32>(Wo, d * 64 + c);
  // attn_out = ctx@Wo + bo + x1 ; x2 = x1 + attn_out (faithful double residual)
  float x2 = 2.f * x1v + proj;
  float mu = wred_sum(x2) * 0.015625f;
  float dv = x2 - mu;
  float var = wred_sum(dv * dv) * 0.015625f;
  float x3 = dv * rsqrtf(var + 1e-5f) * ldf<F32>(ln2w, c) + ldf<F32>(ln2b, c);
  x3s[w][c] = x3;
  __syncthreads();
#pragma unroll
  for (int cc = 0; cc < 4; ++cc){
    const int col = cc * 64 + c;
    float h1 = ldf<F32>(b1, col);
#pragma unroll 8
    for (int d = 0; d < 64; ++d) h1 += x3s[w][d] * ldf<F32>(W1, d * 256 + col);
    gs[w][col] = 0.5f * h1 * (1.f + erff(h1 * 0.70710678f));   // exact gelu
  }
  __syncthreads();
  float ff = ldf<F32>(b2, c);
#pragma unroll 8
  for (int f = 0; f < 256; ++f) ff += gs[w][f] * ldf<F32>(W2, f * 64 + c);
  float res = x2 + ff;
  if constexpr (F32) ((float*)out)[(size_t)row * 64 + c] = res;
  else               ((bf16*)out)[(size_t)row * 64 + c] = __float2bfloat16(res);
}

__global__ __launch_bounds__(256) void k_ffn(
    const void* xprobe,
    const float* ctxf, const float* x1f,
    const void* Wo, const void* bo, const void* W1, const void* b1,
    const void* W2, const void* b2, const void* ln2w, const void* ln2b,
    void* out)
{
  __shared__ float cs[4][64];
  __shared__ float x3s[4][64];
  __shared__ float gs[4][256];
  if (detect_f32(xprobe))
    ffn_body<1>(ctxf, x1f, Wo, bo, W1, b1, W2, b2, ln2w, ln2b, out, cs, x3s, gs);
  else
    ffn_body<0>(ctxf, x1f, Wo, bo, W1, b1, W2, b2, ln2w, ln2b, out, cs, x3s, gs);
}

extern "C" void kernel_launch(void* const* d_in, const int* in_sizes, int n_in,
                              void* d_out, int out_size, void* d_ws, size_t ws_size,
                              hipStream_t stream)
{
  (void)in_sizes; (void)n_in; (void)out_size; (void)ws_size;
  const void* x    = d_in[0];
  const int*  mask = (const int*)d_in[1];
  const void* Wq = d_in[2];
  const void* bq = d_in[3];
  const void* Wk = d_in[4];
  const void* bk = d_in[5];
  const void* Wv = d_in[6];
  const void* bv = d_in[7];
  const void* Wo = d_in[8];
  const void* bo = d_in[9];
  const void* W1 = d_in[10];
  const void* b1 = d_in[11];
  const void* W2 = d_in[12];
  const void* b2 = d_in[13];
  const void* ln1w = d_in[14];
  const void* ln1b = d_in[15];
  const void* ln2w = d_in[16];
  const void* ln2b = d_in[17];

  char* ws = (char*)d_ws;
  float* x1f = (float*)(ws + 0);               // 2 MB    [B][S][64] f32
  bf16*  Qb  = (bf16*)(ws + (2u << 20));       // 1 MB    [B][S][64] bf16 (pre-scaled)
  bf16*  Kb  = (bf16*)(ws + (3u << 20));       // 1 MB
  bf16*  Vb  = (bf16*)(ws + (4u << 20));       // 1 MB
  bf16*  Vt9 = (bf16*)(ws + (5u << 20));       // 1.25 MB [bh][9][S] bf16, row8=ones
  float* ctxf= (float*)(ws + (25u << 18));     // 2 MB    [B][H][S][8] f32  (@6.25MB)
  ull*   pm  = (ull*)(ws + (33u << 18));       // 2 MB    [B*S][32] packed mask (@8.25MB)

  k_prep<<<4096, 256, 0, stream>>>(mask, pm, x, Wq, bq, Wk, bk, Wv, bv, ln1w, ln1b, x1f, Qb, Kb, Vb);
  k_vt<<<256, 256, 0, stream>>>(Vb, Vt9);
  k_attn<<<512, 512, 0, stream>>>(Qb, Kb, Vt9, pm, ctxf);
  k_ffn<<<2048, 256, 0, stream>>>(x, ctxf, x1f, Wo, bo, W1, b1, W2, b2, ln2w, ln2b, d_out);
}

// Round 7
// 123.586 us; speedup vs baseline: 1.5139x; 1.5139x over previous
//
#include <hip/hip_runtime.h>
#include <hip/hip_bf16.h>

#define SEQ 2048

typedef short s4v __attribute__((ext_vector_type(4)));
typedef float f32x4 __attribute__((ext_vector_type(4)));

using bf16 = __hip_bfloat16;
using ull = unsigned long long;

__device__ __forceinline__ float wred_sum(float v){
#pragma unroll
  for (int i = 1; i < 64; i <<= 1) v += __shfl_xor(v, i, 64);
  return v;
}

__device__ __forceinline__ float wred_max(float v){
#pragma unroll
  for (int i = 1; i < 64; i <<= 1) v = fmaxf(v, __shfl_xor(v, i, 64));
  return v;
}

// Detect whether a "float" input buffer is really f32 (1) or bf16 (0).
__device__ __forceinline__ int detect_f32(const void* xraw){
  const unsigned short* p = (const unsigned short*)xraw;
  const int lane = threadIdx.x & 63;
  float mx = 0.f;
#pragma unroll
  for (int i = 0; i < 2; ++i){
    unsigned u = ((unsigned)p[lane * 2 + i]) << 16;
    float f = fabsf(__uint_as_float(u));
    if (!(f < 1e30f)) f = 1e30f;       // NaN/Inf -> large
    mx = fmaxf(mx, f);
  }
  mx = wred_max(mx);
  return mx > 1e3f ? 1 : 0;
}

template<int F32>
__device__ __forceinline__ float ldf(const void* p, int i){
  if constexpr (F32) return ((const float*)p)[i];
  else return __bfloat162float(((const bf16*)p)[i]);
}

// log2(e)/sqrt(dk) folded into Q at projection time
#define QSCALE 0.5101129340352065f

// ---------------- Kernel P: fused mask-pack + LN1/QKV (packed outputs) ---------
// blocks 0..2047: bit-pack mask -> pm[(b*128+qt)*512 + qi*2 + kt*32 + hf] (ull)
// blocks 2048..4095: LN1 + QKV -> Qp/Kp/Vp [bh][s][8] packed per head.
template<int F32>
__device__ __forceinline__ void ln_qkv_body(
    const void* x,
    const void* Wq, const void* bq,
    const void* Wk, const void* bk,
    const void* Wv, const void* bv,
    const void* ln1w, const void* ln1b,
    float* x1f, bf16* Qp, bf16* Kp, bf16* Vp, float (*xs)[64])
{
  const int w = threadIdx.x >> 6, lane = threadIdx.x & 63;
  const int row = (blockIdx.x - 2048) * 4 + w;        // 0..8191 (= b*2048+s)
  float xv = ldf<F32>(x, row * 64 + lane);
  float mu = wred_sum(xv) * 0.015625f;
  float dv = xv - mu;
  float var = wred_sum(dv * dv) * 0.015625f;
  float x1 = dv * rsqrtf(var + 1e-5f) * ldf<F32>(ln1w, lane) + ldf<F32>(ln1b, lane);
  x1f[(size_t)row * 64 + lane] = x1;
  xs[w][lane] = x1;
  __syncthreads();
  float q = ldf<F32>(bq, lane);
  float k = ldf<F32>(bk, lane);
  float v = ldf<F32>(bv, lane);
#pragma unroll 16
  for (int d = 0; d < 64; ++d){
    float xd = xs[w][d];                              // LDS broadcast
    q += xd * ldf<F32>(Wq, d * 64 + lane);            // contiguous per d
    k += xd * ldf<F32>(Wk, d * 64 + lane);
    v += xd * ldf<F32>(Wv, d * 64 + lane);
  }
  // packed per-head layout [bh][s][8]
  const int bq_ = row >> 11, sq = row & 2047;
  const int hh = lane >> 3, dd = lane & 7;
  const size_t pidx = (((size_t)(bq_ * 8 + hh)) * SEQ + sq) * 8 + dd;
  Qp[pidx] = __float2bfloat16(q * QSCALE);            // pre-scaled
  Kp[pidx] = __float2bfloat16(k);
  Vp[pidx] = __float2bfloat16(v);
}

__global__ __launch_bounds__(256) void k_prep(
    const int* __restrict__ mask, ull* __restrict__ pm,
    const void* x, const void* Wq, const void* bq, const void* Wk, const void* bk,
    const void* Wv, const void* bv, const void* ln1w, const void* ln1b,
    float* x1f, bf16* Qp, bf16* Kp, bf16* Vp)
{
  __shared__ float xs[4][64];
  const int w = threadIdx.x >> 6, lane = threadIdx.x & 63;
  if (blockIdx.x < 2048){
    const int row = blockIdx.x * 4 + w;               // 0..8191 (= b*2048+q)
    const int b = row >> 11, q = row & 2047;
    const int* rp = mask + (size_t)row * SEQ;
    ull* op = pm + ((size_t)(b * 128 + (q >> 4))) * 512 + (q & 15) * 2;
#pragma unroll
    for (int it = 0; it < 8; ++it){
      const int c0 = it * 256 + lane;
      ull m0 = __ballot(rp[c0] == 1);
      ull m1 = __ballot(rp[c0 + 64] == 1);
      ull m2 = __ballot(rp[c0 + 128] == 1);
      ull m3 = __ballot(rp[c0 + 192] == 1);
      if (lane == 0){
#pragma unroll
        for (int j = 0; j < 4; ++j){
          const int wi = it * 4 + j;
          const ull mv = (j == 0) ? m0 : (j == 1) ? m1 : (j == 2) ? m2 : m3;
          op[(wi >> 1) * 32 + (wi & 1)] = mv;
        }
      }
    }
    return;
  }
  if (detect_f32(x))
    ln_qkv_body<1>(x, Wq, bq, Wk, bk, Wv, bv, ln1w, ln1b, x1f, Qp, Kp, Vp, xs);
  else
    ln_qkv_body<0>(x, Wq, bq, Wk, bk, Wv, bv, ln1w, ln1b, x1f, Qp, Kp, Vp, xs);
}

// ------- Kernel A2: V -> Vti[bh][tt=s/16][9][16] interleaved, row 8 = ones -----
__global__ __launch_bounds__(256) void k_vt(const bf16* __restrict__ Vp, bf16* __restrict__ Vti)
{
  const int bh = blockIdx.x >> 3;
  const int s0 = (blockIdx.x & 7) * 256;
  const int t = threadIdx.x;
  __shared__ unsigned lds[256][9];                 // [s][d], pad to 9
  uint4 vrow = *reinterpret_cast<const uint4*>(Vp + ((size_t)bh * SEQ + s0 + t) * 8);
  const unsigned short* hp = (const unsigned short*)&vrow;
#pragma unroll
  for (int i = 0; i < 8; ++i) lds[t][i] = (unsigned)hp[i];
  __syncthreads();
  if (t < 144){
    const int gg = t / 9, dd = t % 9;              // 16 groups x 9 rows
    unsigned short outv[16];
#pragma unroll
    for (int j = 0; j < 16; ++j)
      outv[j] = (dd < 8) ? (unsigned short)lds[gg * 16 + j][dd] : (unsigned short)0x3F80;
    uint4 o0, o1;
    o0.x = outv[0] | ((unsigned)outv[1] << 16);  o0.y = outv[2] | ((unsigned)outv[3] << 16);
    o0.z = outv[4] | ((unsigned)outv[5] << 16);  o0.w = outv[6] | ((unsigned)outv[7] << 16);
    o1.x = outv[8] | ((unsigned)outv[9] << 16);  o1.y = outv[10] | ((unsigned)outv[11] << 16);
    o1.z = outv[12] | ((unsigned)outv[13] << 16); o1.w = outv[14] | ((unsigned)outv[15] << 16);
    bf16* dst = Vti + (((size_t)(bh * 128 + (s0 >> 4) + gg)) * 9 + dd) * 16;
    *reinterpret_cast<uint4*>(dst) = o0;
    *(reinterpret_cast<uint4*>(dst) + 1) = o1;
  }
}

// ---------------- Kernel B: flash attention, prefetch-pipelined ----------------
// 256 thr (4 waves = 4 heads); 16 queries/block; fixed-ref softmax (no max/rescale);
// denominator via V ones-row. All tile loads double-buffered a full tile ahead.
#define LOADT(PB, T) do {                                                          \
    const int tt_ = (T);                                                           \
    _Pragma("unroll")                                                              \
    for (int i_ = 0; i_ < 8; ++i_){                                                \
      kf[PB][i_] = *reinterpret_cast<const s4v*>(kb8 + (size_t)(tt_ * 128 + i_ * 16) * 8); \
      vf[PB][i_] = *reinterpret_cast<const s4v*>(vb8 + (size_t)(tt_ * 8 + i_) * 144);      \
    }                                                                              \
    mwv[PB] = pb[tt_ * 16];                                                        \
  } while (0)

#define COMPT(PB) do {                                                             \
    const ull mx_ = (((ull)mwv[PB].y) << 32) | mwv[PB].x;                          \
    const ull my_ = (((ull)mwv[PB].w) << 32) | mwv[PB].z;                          \
    _Pragma("unroll")                                                              \
    for (int c_ = 0; c_ < 2; ++c_){                                                \
      const ull mm_ = c_ ? my_ : mx_;                                              \
      f32x4 st_[4];                                                                \
      _Pragma("unroll")                                                            \
      for (int i_ = 0; i_ < 4; ++i_)                                               \
        st_[i_] = __builtin_amdgcn_mfma_f32_16x16x16bf16_1k(kf[PB][c_ * 4 + i_], qf, zf, 0, 0, 0); \
      _Pragma("unroll")                                                            \
      for (int i_ = 0; i_ < 4; ++i_){                                              \
        const unsigned b4_ = (unsigned)(mm_ >> (16 * i_ + sh4)) & 0xFu;            \
        float p0_ = (b4_ & 1u) ? 0.f : exp2f(st_[i_][0]);                          \
        float p1_ = (b4_ & 2u) ? 0.f : exp2f(st_[i_][1]);                          \
        float p2_ = (b4_ & 4u) ? 0.f : exp2f(st_[i_][2]);                          \
        float p3_ = (b4_ & 8u) ? 0.f : exp2f(st_[i_][3]);                          \
        union { uint2 u; s4v s; } pu_;                                             \
        asm("v_cvt_pk_bf16_f32 %0, %1, %2" : "=v"(pu_.u.x) : "v"(p0_), "v"(p1_));  \
        asm("v_cvt_pk_bf16_f32 %0, %1, %2" : "=v"(pu_.u.y) : "v"(p2_), "v"(p3_));  \
        if (i_ & 1) accB = __builtin_amdgcn_mfma_f32_16x16x16bf16_1k(vf[PB][c_ * 4 + i_], pu_.s, accB, 0, 0, 0); \
        else        accA = __builtin_amdgcn_mfma_f32_16x16x16bf16_1k(vf[PB][c_ * 4 + i_], pu_.s, accA, 0, 0, 0); \
      }                                                                            \
    }                                                                              \
  } while (0)

__global__ __launch_bounds__(256, 4) void k_attn(
    const bf16* __restrict__ Qp, const bf16* __restrict__ Kp,
    const bf16* __restrict__ Vti, const uint4* __restrict__ pmi,
    float* __restrict__ ctxf)
{
  const int blk = blockIdx.x;                 // 1024 = b(4) x qt(128) x hg(2)
  const int hg = blk & 1;
  const int qt = (blk >> 1) & 127;
  const int b  = blk >> 8;
  const int h  = hg * 4 + (threadIdx.x >> 6);
  const int bh = b * 8 + h;
  const int q0 = qt * 16;
  const int lane = threadIdx.x & 63;
  const int g = lane >> 4, qi = lane & 15;
  const int sh4 = 4 * g;

  s4v qf = {0, 0, 0, 0};
  if (g < 2) qf = *reinterpret_cast<const s4v*>(Qp + ((size_t)(bh * SEQ + q0 + qi)) * 8 + sh4);

  const bf16*  kb8 = Kp + ((size_t)bh * SEQ + qi) * 8 + sh4;
  const bf16*  vb8 = Vti + (size_t)bh * 128 * 144 + qi * 16 + sh4;
  const uint4* pb  = pmi + (size_t)(b * 128 + qt) * 256 + qi;

  f32x4 accA = {0.f, 0.f, 0.f, 0.f};
  f32x4 accB = {0.f, 0.f, 0.f, 0.f};
  const f32x4 zf = {0.f, 0.f, 0.f, 0.f};

  s4v kf[2][8], vf[2][8];
  uint4 mwv[2];

  LOADT(0, 0);
  for (int it2 = 0; it2 < 8; ++it2){
    LOADT(1, (2 * it2 + 1) & 15);
    COMPT(0);
    LOADT(0, (2 * it2 + 2) & 15);
    COMPT(1);
  }

  f32x4 acc;
  acc[0] = accA[0] + accB[0]; acc[1] = accA[1] + accB[1];
  acc[2] = accA[2] + accB[2]; acc[3] = accA[3] + accB[3];
  // denominator lives in D row 8 (lane 32+qi, reg 0), col = query
  const float s = __shfl(acc[0], 32 + qi, 64);
  if (g < 2){
    const float inv = 1.f / s;
    float4 o;
    o.x = acc[0] * inv; o.y = acc[1] * inv; o.z = acc[2] * inv; o.w = acc[3] * inv;
    *reinterpret_cast<float4*>(ctxf + ((size_t)(bh * SEQ + q0 + qi)) * 8 + sh4) = o;
  }
}

// ---------------- Kernel C: Wo + residuals + LN2 + FFN (wave per row) ----------------
template<int F32>
__device__ __forceinline__ void ffn_body(
    const float* ctxf, const float* x1f,
    const void* Wo, const void* bo, const void* W1, const void* b1,
    const void* W2, const void* b2, const void* ln2w, const void* ln2b,
    void* out, float (*cs)[64], float (*x3s)[64], float (*gs)[256])
{
  const int w = threadIdx.x >> 6, c = threadIdx.x & 63;
  const int row = blockIdx.x * 4 + w;
  // ctx.reshape(B,S,D) of contiguous [B,H,S,dk] == flat view: ctx_resh[b,r,c]=ctxf[row*64+c]
  float ctxv = ctxf[(size_t)row * 64 + c];
  float x1v  = x1f[(size_t)row * 64 + c];
  cs[w][c] = ctxv;
  __syncthreads();
  float proj = ldf<F32>(bo, c);
#pragma unroll 8
  for (int d = 0; d < 64; ++d) proj += cs[w][d] * ldf<F32>(Wo, d * 64 + c);
  // attn_out = ctx@Wo + bo + x1 ; x2 = x1 + attn_out (faithful double residual)
  float x2 = 2.f * x1v + proj;
  float mu = wred_sum(x2) * 0.015625f;
  float dv = x2 - mu;
  float var = wred_sum(dv * dv) * 0.015625f;
  float x3 = dv * rsqrtf(var + 1e-5f) * ldf<F32>(ln2w, c) + ldf<F32>(ln2b, c);
  x3s[w][c] = x3;
  __syncthreads();
#pragma unroll
  for (int cc = 0; cc < 4; ++cc){
    const int col = cc * 64 + c;
    float h1 = ldf<F32>(b1, col);
#pragma unroll 8
    for (int d = 0; d < 64; ++d) h1 += x3s[w][d] * ldf<F32>(W1, d * 256 + col);
    gs[w][col] = 0.5f * h1 * (1.f + erff(h1 * 0.70710678f));   // exact gelu
  }
  __syncthreads();
  float ff = ldf<F32>(b2, c);
#pragma unroll 8
  for (int f = 0; f < 256; ++f) ff += gs[w][f] * ldf<F32>(W2, f * 64 + c);
  float res = x2 + ff;
  if constexpr (F32) ((float*)out)[(size_t)row * 64 + c] = res;
  else               ((bf16*)out)[(size_t)row * 64 + c] = __float2bfloat16(res);
}

__global__ __launch_bounds__(256) void k_ffn(
    const void* xprobe,
    const float* ctxf, const float* x1f,
    const void* Wo, const void* bo, const void* W1, const void* b1,
    const void* W2, const void* b2, const void* ln2w, const void* ln2b,
    void* out)
{
  __shared__ float cs[4][64];
  __shared__ float x3s[4][64];
  __shared__ float gs[4][256];
  if (detect_f32(xprobe))
    ffn_body<1>(ctxf, x1f, Wo, bo, W1, b1, W2, b2, ln2w, ln2b, out, cs, x3s, gs);
  else
    ffn_body<0>(ctxf, x1f, Wo, bo, W1, b1, W2, b2, ln2w, ln2b, out, cs, x3s, gs);
}

extern "C" void kernel_launch(void* const* d_in, const int* in_sizes, int n_in,
                              void* d_out, int out_size, void* d_ws, size_t ws_size,
                              hipStream_t stream)
{
  (void)in_sizes; (void)n_in; (void)out_size; (void)ws_size;
  const void* x    = d_in[0];
  const int*  mask = (const int*)d_in[1];
  const void* Wq = d_in[2];
  const void* bq = d_in[3];
  const void* Wk = d_in[4];
  const void* bk = d_in[5];
  const void* Wv = d_in[6];
  const void* bv = d_in[7];
  const void* Wo = d_in[8];
  const void* bo = d_in[9];
  const void* W1 = d_in[10];
  const void* b1 = d_in[11];
  const void* W2 = d_in[12];
  const void* b2 = d_in[13];
  const void* ln1w = d_in[14];
  const void* ln1b = d_in[15];
  const void* ln2w = d_in[16];
  const void* ln2b = d_in[17];

  char* ws = (char*)d_ws;
  float* x1f = (float*)(ws + 0);               // 2 MB     [B][S][64] f32
  bf16*  Qp  = (bf16*)(ws + (2u << 20));       // 1 MB     [bh][s][8] bf16 (pre-scaled)
  bf16*  Kp  = (bf16*)(ws + (3u << 20));       // 1 MB     [bh][s][8]
  bf16*  Vp  = (bf16*)(ws + (4u << 20));       // 1 MB     [bh][s][8]
  bf16*  Vti = (bf16*)(ws + (5u << 20));       // 1.125 MB [bh][tt][9][16], row8=ones
  float* ctxf= (float*)(ws + (25u << 18));     // 2 MB     [B][H][S][8] f32  (@6.25MB)
  ull*   pm  = (ull*)(ws + (33u << 18));       // 2 MB     packed mask (@8.25MB)

  k_prep<<<4096, 256, 0, stream>>>(mask, pm, x, Wq, bq, Wk, bk, Wv, bv, ln1w, ln1b, x1f, Qp, Kp, Vp);
  k_vt<<<256, 256, 0, stream>>>(Vp, Vti);
  k_attn<<<1024, 256, 0, stream>>>(Qp, Kp, Vti, (const uint4*)pm, ctxf);
  k_ffn<<<2048, 256, 0, stream>>>(x, ctxf, x1f, Wo, bo, W1, b1, W2, b2, ln2w, ln2b, d_out);
}